// Round 6
// baseline (560.315 us; speedup 1.0000x reference)
//
#include <hip/hip_runtime.h>
#include <hip/hip_bf16.h>
#include <math.h>

#define N_NODES 50000
#define N_EDGES 1600000
#define IN_CH 128
#define OUT_SZ 64
#define N_TILES 3125   // 50000 / 16
#define NB 782         // ceil(50000/64) buckets of 64 nodes

typedef short bf16x8 __attribute__((ext_vector_type(8)));
typedef float f32x4  __attribute__((ext_vector_type(4)));

// monotone f32 -> u32 mapping for atomicMax on floats
__device__ __forceinline__ unsigned fenc(float x) {
    unsigned u = __float_as_uint(x);
    return (u & 0x80000000u) ? ~u : (u | 0x80000000u);
}
__device__ __forceinline__ float fdec(unsigned u) {
    return __uint_as_float((u & 0x80000000u) ? (u & 0x7fffffffu) : ~u);
}

__device__ __forceinline__ short bfbits(float x) {
    union { __hip_bfloat16 h; short s; } u;
    u.h = __float2bfloat16(x);
    return u.s;
}
__device__ __forceinline__ bf16x8 pack8(const float* f) {
    bf16x8 r;
#pragma unroll
    for (int j = 0; j < 8; ++j) r[j] = bfbits(f[j]);
    return r;
}

// ---------------- K0: zero counters + softmax scalars ----------------
__global__ __launch_bounds__(256) void k_zero(unsigned* pmax1, unsigned* pmax2,
                                              float* psum, unsigned* counts) {
    int i = blockIdx.x * 256 + threadIdx.x;
    if (i < N_NODES) counts[i] = 0u;
    if (i == 0) { *pmax1 = 0u; *pmax2 = 0u; *psum = 0.0f; }
}

// ---------------- K0b: src histogram ----------------
__global__ __launch_bounds__(256) void k_hist(const int* __restrict__ ei,
                                              unsigned* __restrict__ counts) {
    int tid = blockIdx.x * 256 + threadIdx.x;
    int stride = gridDim.x * 256;
    for (int e = tid; e < N_EDGES; e += stride)
        atomicAdd(&counts[ei[e]], 1u);
}

// ---------------- K1: node linears via bf16 MFMA (proven R5) ----------------
__global__ __launch_bounds__(256) void k_gemm(
    const float* __restrict__ seq, const float* __restrict__ Wseq,
    const float* __restrict__ Wres, const float* __restrict__ wf1,
    const float* __restrict__ bf1, const float* __restrict__ wf2,
    const float* __restrict__ bf2, const float* __restrict__ bias,
    const float* __restrict__ bres,
    __hip_bfloat16* __restrict__ sftsh, float* __restrict__ f1,
    float* __restrict__ f2, unsigned* pmax1, unsigned* pmax2,
    float* __restrict__ out)
{
    __shared__ bf16x8 WL[2048];     // 32 KiB
    __shared__ float smax[8];
    const int t = threadIdx.x;

#pragma unroll
    for (int j = 0; j < 8; ++j) {
        int idx = t + j * 256;          // 0..2047
        int ct = idx >> 8;              // col tile 0..7
        int ks = (idx >> 6) & 3;        // k step 0..3
        int li = idx & 63;
        int c = ct * 16 + (li & 15);
        int k0 = ks * 32 + (li >> 4) * 8;
        const float* src = (c < 64) ? (Wseq + c * IN_CH + k0)
                                    : (Wres + (c - 64) * IN_CH + k0);
        float tmp[8];
        *(float4*)tmp = *(const float4*)src;
        *(float4*)(tmp + 4) = *(const float4*)(src + 4);
        WL[idx] = pack8(tmp);
    }
    __syncthreads();

    const int l = t & 63;
    const int wv = t >> 6;
    const int tile = blockIdx.x * 4 + wv;
    const bool active = tile < N_TILES;
    float mx1 = -3.0e38f, mx2 = -3.0e38f;

    if (active) {
        const int row = tile * 16 + (l & 15);
        const int kbase = (l >> 4) * 8;
        f32x4 acc[8];
#pragma unroll
        for (int ct = 0; ct < 8; ++ct) acc[ct] = (f32x4){0.f, 0.f, 0.f, 0.f};

#pragma unroll
        for (int ks = 0; ks < 4; ++ks) {
            const float* ap = seq + (size_t)row * IN_CH + ks * 32 + kbase;
            float tmp[8];
            *(float4*)tmp = *(const float4*)ap;
            *(float4*)(tmp + 4) = *(const float4*)(ap + 4);
            bf16x8 af = pack8(tmp);
#pragma unroll
            for (int ct = 0; ct < 8; ++ct)
                acc[ct] = __builtin_amdgcn_mfma_f32_16x16x32_bf16(
                    af, WL[(ct * 4 + ks) * 64 + l], acc[ct], 0, 0, 0);
        }

        // epilogue: C/D layout col = lane&15, row = (lane>>4)*4 + reg
        const int n0 = tile * 16;
        float w1v[4], w2v[4], bb[4];
#pragma unroll
        for (int ct = 0; ct < 4; ++ct) {
            int oc = ct * 16 + (l & 15);
            w1v[ct] = wf1[oc];
            w2v[ct] = wf2[oc];
            bb[ct] = bias[oc] + bres[oc];
        }
        const float B1 = bf1[0], B2 = bf2[0];
#pragma unroll
        for (int r = 0; r < 4; ++r) {
            int node = n0 + (l >> 4) * 4 + r;
            size_t o = (size_t)node * 64 + (l & 15);
#pragma unroll
            for (int ct = 0; ct < 4; ++ct) {
                sftsh[o + ct * 16] = __float2bfloat16(acc[ct][r]);
                out[o + ct * 16] = acc[ct + 4][r] + bb[ct];
            }
            float t1 = acc[0][r] * w1v[0] + acc[1][r] * w1v[1]
                     + acc[2][r] * w1v[2] + acc[3][r] * w1v[3];
            float t2 = acc[0][r] * w2v[0] + acc[1][r] * w2v[1]
                     + acc[2][r] * w2v[2] + acc[3][r] * w2v[3];
#pragma unroll
            for (int m = 8; m; m >>= 1) {
                t1 += __shfl_xor(t1, m);
                t2 += __shfl_xor(t2, m);
            }
            if ((l & 15) == 0) {
                float F1 = t1 + B1, F2 = t2 + B2;
                f1[node] = F1;
                f2[node] = F2;
                mx1 = fmaxf(mx1, F1);
                mx2 = fmaxf(mx2, F2);
            }
        }
    }

    mx1 = fmaxf(mx1, __shfl_xor(mx1, 16)); mx1 = fmaxf(mx1, __shfl_xor(mx1, 32));
    mx2 = fmaxf(mx2, __shfl_xor(mx2, 16)); mx2 = fmaxf(mx2, __shfl_xor(mx2, 32));
    if (l == 0) { smax[wv] = mx1; smax[4 + wv] = mx2; }
    __syncthreads();
    if (t == 0) {
        atomicMax(pmax1, fenc(fmaxf(fmaxf(smax[0], smax[1]), fmaxf(smax[2], smax[3]))));
        atomicMax(pmax2, fenc(fmaxf(fmaxf(smax[4], smax[5]), fmaxf(smax[6], smax[7]))));
    }
}

// ---------------- K2a: per-bucket sums (wave per bucket of 64 nodes) ----------------
__global__ __launch_bounds__(256) void k_scanA(const unsigned* __restrict__ counts,
                                               unsigned* __restrict__ bucketSum) {
    const int lane = threadIdx.x & 63;
    const int b = (blockIdx.x * 256 + threadIdx.x) >> 6;
    if (b >= NB) return;
    int n = b * 64 + lane;
    unsigned c = (n < N_NODES) ? counts[n] : 0u;
#pragma unroll
    for (int off = 32; off; off >>= 1) c += __shfl_xor(c, off);
    if (lane == 0) bucketSum[b] = c;
}

// ---------------- K2b: single-block scan of 782 bucket sums ----------------
__global__ __launch_bounds__(1024) void k_scanB(const unsigned* __restrict__ bucketSum,
                                                unsigned* __restrict__ bucketOff,
                                                unsigned* __restrict__ cursorB,
                                                unsigned* __restrict__ offs) {
    __shared__ unsigned bs[1024];
    const int t = threadIdx.x;
    unsigned v = (t < NB) ? bucketSum[t] : 0u;
    bs[t] = v;
    __syncthreads();
    for (int off = 1; off < 1024; off <<= 1) {
        unsigned w = (t >= off) ? bs[t - off] : 0u;
        __syncthreads();
        bs[t] += w;
        __syncthreads();
    }
    if (t < NB) {
        unsigned excl = bs[t] - v;
        bucketOff[t] = excl;
        cursorB[t] = excl;
    }
    if (t == 0) {
        bucketOff[NB] = bs[NB - 1];
        offs[N_NODES] = bs[NB - 1];
    }
}

// ---------------- K2c: per-node offsets (wave-scan per bucket) ----------------
__global__ __launch_bounds__(256) void k_scanC(const unsigned* __restrict__ counts,
                                               const unsigned* __restrict__ bucketOff,
                                               unsigned* __restrict__ offs) {
    const int lane = threadIdx.x & 63;
    const int b = (blockIdx.x * 256 + threadIdx.x) >> 6;
    if (b >= NB) return;
    int n = b * 64 + lane;
    unsigned c = (n < N_NODES) ? counts[n] : 0u;
    unsigned incl = c;
#pragma unroll
    for (int off = 1; off < 64; off <<= 1) {
        unsigned w = __shfl_up(incl, off);
        if (lane >= off) incl += w;
    }
    if (n < N_NODES) offs[n] = bucketOff[b] + (incl - c);
}

// ---------------- K3a: scatter (src,dst) pairs into bucket regions ----------------
__global__ __launch_bounds__(256) void k_bucket(const int* __restrict__ ei,
                                                unsigned* __restrict__ cursorB,
                                                unsigned* __restrict__ pairs) {
    int tid = blockIdx.x * 256 + threadIdx.x;
    int stride = gridDim.x * 256;
    for (int e = tid; e < N_EDGES; e += stride) {
        unsigned src = (unsigned)ei[e];
        unsigned dst = (unsigned)ei[N_EDGES + e];
        unsigned pos = atomicAdd(&cursorB[src >> 6], 1u);
        pairs[pos] = (src << 16) | dst;
    }
}

// ---------------- K3b: per-bucket counting sort + fused exp-sum ----------------
// one block per bucket; LDS cursors for the bucket's 64 nodes
__global__ __launch_bounds__(256) void k_sortsum(
    const unsigned* __restrict__ pairs, const unsigned* __restrict__ bucketOff,
    const unsigned* __restrict__ offs, const float* __restrict__ f1,
    const float* __restrict__ f2, const unsigned* __restrict__ pmax1,
    const unsigned* __restrict__ pmax2, unsigned short* __restrict__ sDst,
    float* psum)
{
    __shared__ unsigned lcur[64];
    __shared__ float f1loc[64];
    __shared__ float red[4];
    const int t = threadIdx.x;
    const int b = blockIdx.x;
    const int base = b * 64;
    if (t < 64) {
        int n = base + t;
        if (n < N_NODES) {
            lcur[t] = offs[n];
            f1loc[t] = f1[n];
        }
    }
    __syncthreads();

    float M = fdec(*pmax1) + fdec(*pmax2);
    M = (M > 0.f) ? M : 0.01f * M;
    const unsigned eb = bucketOff[b];
    const unsigned ee = bucketOff[b + 1];
    float ls = 0.f;
    for (unsigned i = eb + t; i < ee; i += 256) {
        unsigned p = pairs[i];
        unsigned src = p >> 16;
        unsigned dst = p & 0xffffu;
        unsigned pos = atomicAdd(&lcur[src - base], 1u);
        sDst[pos] = (unsigned short)dst;
        float x = f1loc[src - base] + f2[dst];
        x = (x > 0.f) ? x : 0.01f * x;
        ls += __expf(x - M);
    }
#pragma unroll
    for (int off = 32; off; off >>= 1) ls += __shfl_xor(ls, off);
    if ((t & 63) == 0) red[t >> 6] = ls;
    __syncthreads();
    if (t == 0) {
        ls = red[0] + red[1] + red[2] + red[3];
        unsafeAtomicAdd(psum, ls);
    }
}

// ---------------- K4: per-node accumulate + ELU, 8-deep pipelined gathers ----------------
__global__ __launch_bounds__(256) void k_acc(
    const unsigned* __restrict__ offs, const unsigned short* __restrict__ sDst,
    const float* __restrict__ f1, const float* __restrict__ f2,
    const __hip_bfloat16* __restrict__ sftsh, const unsigned* __restrict__ pmax1,
    const unsigned* __restrict__ pmax2, const float* __restrict__ psum,
    float* __restrict__ out)
{
    const int lane = threadIdx.x & 63;
    const int n = (blockIdx.x * 256 + threadIdx.x) >> 6;
    if (n >= N_NODES) return;
    float M = fdec(*pmax1) + fdec(*pmax2);
    M = (M > 0.f) ? M : 0.01f * M;
    const float inv = 1.0f / (*psum);
    const unsigned b = offs[n];
    const unsigned e = offs[n + 1];
    const float f1n = f1[n];

    float acc = 0.f;
    for (unsigned e0 = b; e0 < e; e0 += 64) {
        const int cnt = (int)min(64u, e - e0);
        int dst = 0;
        float coef = 0.f;               // lanes >= cnt contribute 0
        if (lane < cnt) {
            dst = (int)sDst[e0 + lane];
            float x = f1n + f2[dst];
            x = (x > 0.f) ? x : 0.01f * x;
            coef = __expf(x - M) * inv;
        }
        const int nb = (cnt + 7) & ~7;  // ragged tail handled by coef==0 lanes
        for (int j = 0; j < nb; j += 8) {
            int d0 = __shfl(dst, j);     float c0 = __shfl(coef, j);
            int d1 = __shfl(dst, j + 1); float c1 = __shfl(coef, j + 1);
            int d2 = __shfl(dst, j + 2); float c2 = __shfl(coef, j + 2);
            int d3 = __shfl(dst, j + 3); float c3 = __shfl(coef, j + 3);
            int d4 = __shfl(dst, j + 4); float c4 = __shfl(coef, j + 4);
            int d5 = __shfl(dst, j + 5); float c5 = __shfl(coef, j + 5);
            int d6 = __shfl(dst, j + 6); float c6 = __shfl(coef, j + 6);
            int d7 = __shfl(dst, j + 7); float c7 = __shfl(coef, j + 7);
            float v0 = __bfloat162float(sftsh[(size_t)d0 * 64 + lane]);
            float v1 = __bfloat162float(sftsh[(size_t)d1 * 64 + lane]);
            float v2 = __bfloat162float(sftsh[(size_t)d2 * 64 + lane]);
            float v3 = __bfloat162float(sftsh[(size_t)d3 * 64 + lane]);
            float v4 = __bfloat162float(sftsh[(size_t)d4 * 64 + lane]);
            float v5 = __bfloat162float(sftsh[(size_t)d5 * 64 + lane]);
            float v6 = __bfloat162float(sftsh[(size_t)d6 * 64 + lane]);
            float v7 = __bfloat162float(sftsh[(size_t)d7 * 64 + lane]);
            acc = fmaf(c0, v0, acc); acc = fmaf(c1, v1, acc);
            acc = fmaf(c2, v2, acc); acc = fmaf(c3, v3, acc);
            acc = fmaf(c4, v4, acc); acc = fmaf(c5, v5, acc);
            acc = fmaf(c6, v6, acc); acc = fmaf(c7, v7, acc);
        }
    }
    const size_t idx = (size_t)n * 64 + lane;
    float x = out[idx] + acc;
    out[idx] = (x > 0.f) ? x : expm1f(x);
}

extern "C" void kernel_launch(void* const* d_in, const int* in_sizes, int n_in,
                              void* d_out, int out_size, void* d_ws, size_t ws_size,
                              hipStream_t stream) {
    const float* seq  = (const float*)d_in[0];
    const int*   ei   = (const int*)d_in[1];
    const float* Wseq = (const float*)d_in[2];
    const float* wf1  = (const float*)d_in[3];
    const float* bf1  = (const float*)d_in[4];
    const float* wf2  = (const float*)d_in[5];
    const float* bf2  = (const float*)d_in[6];
    const float* bias = (const float*)d_in[7];
    const float* Wres = (const float*)d_in[8];
    const float* bres = (const float*)d_in[9];
    float* out = (float*)d_out;

    // ws layout (u32 units unless noted)
    unsigned* pmax1     = (unsigned*)d_ws;
    unsigned* pmax2     = (unsigned*)d_ws + 1;
    float*    psum      = (float*)d_ws + 2;
    unsigned* counts    = (unsigned*)d_ws + 16;
    unsigned* offs      = counts + N_NODES;               // N_NODES+1
    unsigned* bucketSum = offs + N_NODES + 1;             // NB
    unsigned* bucketOff = bucketSum + NB;                 // NB+1
    unsigned* cursorB   = bucketOff + NB + 1;             // NB
    unsigned* pairs     = cursorB + NB;                   // N_EDGES u32
    unsigned short* sDst = (unsigned short*)(pairs + N_EDGES);     // N_EDGES u16
    __hip_bfloat16* sftsh = (__hip_bfloat16*)(sDst + N_EDGES);     // N*64 bf16
    float*    f1        = (float*)(sftsh + (size_t)N_NODES * 64);
    float*    f2        = f1 + N_NODES;
    // total ~17 MB

    k_zero<<<196, 256, 0, stream>>>(pmax1, pmax2, psum, counts);
    k_hist<<<2048, 256, 0, stream>>>(ei, counts);
    k_gemm<<<782, 256, 0, stream>>>(seq, Wseq, Wres, wf1, bf1, wf2, bf2, bias,
                                    bres, sftsh, f1, f2, pmax1, pmax2, out);
    k_scanA<<<196, 256, 0, stream>>>(counts, bucketSum);
    k_scanB<<<1, 1024, 0, stream>>>(bucketSum, bucketOff, cursorB, offs);
    k_scanC<<<196, 256, 0, stream>>>(counts, bucketOff, offs);
    k_bucket<<<2048, 256, 0, stream>>>(ei, cursorB, pairs);
    k_sortsum<<<NB, 256, 0, stream>>>(pairs, bucketOff, offs, f1, f2,
                                      pmax1, pmax2, sDst, psum);
    k_acc<<<12500, 256, 0, stream>>>(offs, sDst, f1, f2, sftsh, pmax1, pmax2, psum, out);
}

// Round 7
// 240.566 us; speedup vs baseline: 2.3292x; 2.3292x over previous
//
#include <hip/hip_runtime.h>
#include <hip/hip_bf16.h>
#include <math.h>

#define N_NODES 50000
#define N_EDGES 1600000
#define IN_CH 128
#define OUT_SZ 64
#define N_TILES 3125   // 50000 / 16
#define NB 782         // ceil(50000/64) buckets of 64 nodes

typedef short bf16x8 __attribute__((ext_vector_type(8)));
typedef float f32x4  __attribute__((ext_vector_type(4)));

// monotone f32 -> u32 mapping for atomicMax on floats
__device__ __forceinline__ unsigned fenc(float x) {
    unsigned u = __float_as_uint(x);
    return (u & 0x80000000u) ? ~u : (u | 0x80000000u);
}
__device__ __forceinline__ float fdec(unsigned u) {
    return __uint_as_float((u & 0x80000000u) ? (u & 0x7fffffffu) : ~u);
}

__device__ __forceinline__ short bfbits(float x) {
    union { __hip_bfloat16 h; short s; } u;
    u.h = __float2bfloat16(x);
    return u.s;
}
__device__ __forceinline__ bf16x8 pack8(const float* f) {
    bf16x8 r;
#pragma unroll
    for (int j = 0; j < 8; ++j) r[j] = bfbits(f[j]);
    return r;
}

// ---------------- K0: zero counters + softmax scalars ----------------
__global__ __launch_bounds__(256) void k_zero(unsigned* pmax1, unsigned* pmax2,
                                              float* psum, unsigned* counts) {
    int i = blockIdx.x * 256 + threadIdx.x;
    if (i < N_NODES) counts[i] = 0u;
    if (i == 0) { *pmax1 = 0u; *pmax2 = 0u; *psum = 0.0f; }
}

// ---------------- K0b: src histogram ----------------
__global__ __launch_bounds__(256) void k_hist(const int* __restrict__ ei,
                                              unsigned* __restrict__ counts) {
    int tid = blockIdx.x * 256 + threadIdx.x;
    int stride = gridDim.x * 256;
    for (int e = tid; e < N_EDGES; e += stride)
        atomicAdd(&counts[ei[e]], 1u);
}

// ---------------- K1: node linears via bf16 MFMA (proven R5) ----------------
__global__ __launch_bounds__(256) void k_gemm(
    const float* __restrict__ seq, const float* __restrict__ Wseq,
    const float* __restrict__ Wres, const float* __restrict__ wf1,
    const float* __restrict__ bf1, const float* __restrict__ wf2,
    const float* __restrict__ bf2, const float* __restrict__ bias,
    const float* __restrict__ bres,
    __hip_bfloat16* __restrict__ sftsh, float* __restrict__ f1,
    float* __restrict__ f2, unsigned* pmax1, unsigned* pmax2,
    float* __restrict__ out)
{
    __shared__ bf16x8 WL[2048];     // 32 KiB
    __shared__ float smax[8];
    const int t = threadIdx.x;

#pragma unroll
    for (int j = 0; j < 8; ++j) {
        int idx = t + j * 256;          // 0..2047
        int ct = idx >> 8;              // col tile 0..7
        int ks = (idx >> 6) & 3;        // k step 0..3
        int li = idx & 63;
        int c = ct * 16 + (li & 15);
        int k0 = ks * 32 + (li >> 4) * 8;
        const float* src = (c < 64) ? (Wseq + c * IN_CH + k0)
                                    : (Wres + (c - 64) * IN_CH + k0);
        float tmp[8];
        *(float4*)tmp = *(const float4*)src;
        *(float4*)(tmp + 4) = *(const float4*)(src + 4);
        WL[idx] = pack8(tmp);
    }
    __syncthreads();

    const int l = t & 63;
    const int wv = t >> 6;
    const int tile = blockIdx.x * 4 + wv;
    const bool active = tile < N_TILES;
    float mx1 = -3.0e38f, mx2 = -3.0e38f;

    if (active) {
        const int row = tile * 16 + (l & 15);
        const int kbase = (l >> 4) * 8;
        f32x4 acc[8];
#pragma unroll
        for (int ct = 0; ct < 8; ++ct) acc[ct] = (f32x4){0.f, 0.f, 0.f, 0.f};

#pragma unroll
        for (int ks = 0; ks < 4; ++ks) {
            const float* ap = seq + (size_t)row * IN_CH + ks * 32 + kbase;
            float tmp[8];
            *(float4*)tmp = *(const float4*)ap;
            *(float4*)(tmp + 4) = *(const float4*)(ap + 4);
            bf16x8 af = pack8(tmp);
#pragma unroll
            for (int ct = 0; ct < 8; ++ct)
                acc[ct] = __builtin_amdgcn_mfma_f32_16x16x32_bf16(
                    af, WL[(ct * 4 + ks) * 64 + l], acc[ct], 0, 0, 0);
        }

        // epilogue: C/D layout col = lane&15, row = (lane>>4)*4 + reg
        const int n0 = tile * 16;
        float w1v[4], w2v[4], bb[4];
#pragma unroll
        for (int ct = 0; ct < 4; ++ct) {
            int oc = ct * 16 + (l & 15);
            w1v[ct] = wf1[oc];
            w2v[ct] = wf2[oc];
            bb[ct] = bias[oc] + bres[oc];
        }
        const float B1 = bf1[0], B2 = bf2[0];
#pragma unroll
        for (int r = 0; r < 4; ++r) {
            int node = n0 + (l >> 4) * 4 + r;
            size_t o = (size_t)node * 64 + (l & 15);
#pragma unroll
            for (int ct = 0; ct < 4; ++ct) {
                sftsh[o + ct * 16] = __float2bfloat16(acc[ct][r]);
                out[o + ct * 16] = acc[ct + 4][r] + bb[ct];
            }
            float t1 = acc[0][r] * w1v[0] + acc[1][r] * w1v[1]
                     + acc[2][r] * w1v[2] + acc[3][r] * w1v[3];
            float t2 = acc[0][r] * w2v[0] + acc[1][r] * w2v[1]
                     + acc[2][r] * w2v[2] + acc[3][r] * w2v[3];
#pragma unroll
            for (int m = 8; m; m >>= 1) {
                t1 += __shfl_xor(t1, m);
                t2 += __shfl_xor(t2, m);
            }
            if ((l & 15) == 0) {
                float F1 = t1 + B1, F2 = t2 + B2;
                f1[node] = F1;
                f2[node] = F2;
                mx1 = fmaxf(mx1, F1);
                mx2 = fmaxf(mx2, F2);
            }
        }
    }

    mx1 = fmaxf(mx1, __shfl_xor(mx1, 16)); mx1 = fmaxf(mx1, __shfl_xor(mx1, 32));
    mx2 = fmaxf(mx2, __shfl_xor(mx2, 16)); mx2 = fmaxf(mx2, __shfl_xor(mx2, 32));
    if (l == 0) { smax[wv] = mx1; smax[4 + wv] = mx2; }
    __syncthreads();
    if (t == 0) {
        atomicMax(pmax1, fenc(fmaxf(fmaxf(smax[0], smax[1]), fmaxf(smax[2], smax[3]))));
        atomicMax(pmax2, fenc(fmaxf(fmaxf(smax[4], smax[5]), fmaxf(smax[6], smax[7]))));
    }
}

// ---------------- K2a: per-bucket sums (wave per bucket of 64 nodes) ----------------
__global__ __launch_bounds__(256) void k_scanA(const unsigned* __restrict__ counts,
                                               unsigned* __restrict__ bucketSum) {
    const int lane = threadIdx.x & 63;
    const int b = (blockIdx.x * 256 + threadIdx.x) >> 6;
    if (b >= NB) return;
    int n = b * 64 + lane;
    unsigned c = (n < N_NODES) ? counts[n] : 0u;
#pragma unroll
    for (int off = 32; off; off >>= 1) c += __shfl_xor(c, off);
    if (lane == 0) bucketSum[b] = c;
}

// ---------------- K2b: single-block scan of 782 bucket sums ----------------
__global__ __launch_bounds__(1024) void k_scanB(const unsigned* __restrict__ bucketSum,
                                                unsigned* __restrict__ bucketOff,
                                                unsigned* __restrict__ offs) {
    __shared__ unsigned bs[1024];
    const int t = threadIdx.x;
    unsigned v = (t < NB) ? bucketSum[t] : 0u;
    bs[t] = v;
    __syncthreads();
    for (int off = 1; off < 1024; off <<= 1) {
        unsigned w = (t >= off) ? bs[t - off] : 0u;
        __syncthreads();
        bs[t] += w;
        __syncthreads();
    }
    if (t < NB) bucketOff[t] = bs[t] - v;
    if (t == 0) {
        bucketOff[NB] = bs[NB - 1];
        offs[N_NODES] = bs[NB - 1];
    }
}

// ---------------- K2c: per-node offsets + cursor (wave-scan per bucket) ----------------
__global__ __launch_bounds__(256) void k_scanC(const unsigned* __restrict__ counts,
                                               const unsigned* __restrict__ bucketOff,
                                               unsigned* __restrict__ offs,
                                               unsigned* __restrict__ cursor) {
    const int lane = threadIdx.x & 63;
    const int b = (blockIdx.x * 256 + threadIdx.x) >> 6;
    if (b >= NB) return;
    int n = b * 64 + lane;
    unsigned c = (n < N_NODES) ? counts[n] : 0u;
    unsigned incl = c;
#pragma unroll
    for (int off = 1; off < 64; off <<= 1) {
        unsigned w = __shfl_up(incl, off);
        if (lane >= off) incl += w;
    }
    if (n < N_NODES) {
        unsigned o = bucketOff[b] + (incl - c);
        offs[n] = o;
        cursor[n] = o;
    }
}

// ---------------- K3: place dst (u16) into src-sorted order + sum exp ----------------
__global__ __launch_bounds__(256) void k_placesum(
    const int* __restrict__ ei, const float* __restrict__ f1,
    const float* __restrict__ f2, const unsigned* __restrict__ pmax1,
    const unsigned* __restrict__ pmax2, unsigned* __restrict__ cursor,
    unsigned short* __restrict__ sDst, float* psum)
{
    float M = fdec(*pmax1) + fdec(*pmax2);
    M = (M > 0.f) ? M : 0.01f * M;          // LRelu of upper bound: valid shift constant
    int tid = blockIdx.x * 256 + threadIdx.x;
    int stride = gridDim.x * 256;
    float ls = 0.f;
    for (int e = tid; e < N_EDGES; e += stride) {
        int src = ei[e];
        int dst = ei[N_EDGES + e];
        float x = f1[src] + f2[dst];
        x = (x > 0.f) ? x : 0.01f * x;
        ls += __expf(x - M);
        unsigned pos = atomicAdd(&cursor[src], 1u);
        sDst[pos] = (unsigned short)dst;
    }
#pragma unroll
    for (int off = 32; off; off >>= 1) ls += __shfl_xor(ls, off);
    __shared__ float red[4];
    if ((threadIdx.x & 63) == 0) red[threadIdx.x >> 6] = ls;
    __syncthreads();
    if (threadIdx.x == 0) {
        ls = red[0] + red[1] + red[2] + red[3];
        unsafeAtomicAdd(psum, ls);
    }
}

// ---------------- K4: per-node accumulate + ELU, 8-deep pipelined gathers ----------------
__global__ __launch_bounds__(256) void k_acc(
    const unsigned* __restrict__ offs, const unsigned short* __restrict__ sDst,
    const float* __restrict__ f1, const float* __restrict__ f2,
    const __hip_bfloat16* __restrict__ sftsh, const unsigned* __restrict__ pmax1,
    const unsigned* __restrict__ pmax2, const float* __restrict__ psum,
    float* __restrict__ out)
{
    const int lane = threadIdx.x & 63;
    const int n = (blockIdx.x * 256 + threadIdx.x) >> 6;
    if (n >= N_NODES) return;
    float M = fdec(*pmax1) + fdec(*pmax2);
    M = (M > 0.f) ? M : 0.01f * M;
    const float inv = 1.0f / (*psum);
    const unsigned b = offs[n];
    const unsigned e = offs[n + 1];
    const float f1n = f1[n];

    float acc = 0.f;
    for (unsigned e0 = b; e0 < e; e0 += 64) {
        const int cnt = (int)min(64u, e - e0);
        int dst = 0;
        float coef = 0.f;               // lanes >= cnt contribute 0
        if (lane < cnt) {
            dst = (int)sDst[e0 + lane];
            float x = f1n + f2[dst];
            x = (x > 0.f) ? x : 0.01f * x;
            coef = __expf(x - M) * inv;
        }
        const int nb = (cnt + 7) & ~7;  // ragged tail handled by coef==0 lanes
        for (int j = 0; j < nb; j += 8) {
            int d0 = __shfl(dst, j);     float c0 = __shfl(coef, j);
            int d1 = __shfl(dst, j + 1); float c1 = __shfl(coef, j + 1);
            int d2 = __shfl(dst, j + 2); float c2 = __shfl(coef, j + 2);
            int d3 = __shfl(dst, j + 3); float c3 = __shfl(coef, j + 3);
            int d4 = __shfl(dst, j + 4); float c4 = __shfl(coef, j + 4);
            int d5 = __shfl(dst, j + 5); float c5 = __shfl(coef, j + 5);
            int d6 = __shfl(dst, j + 6); float c6 = __shfl(coef, j + 6);
            int d7 = __shfl(dst, j + 7); float c7 = __shfl(coef, j + 7);
            float v0 = __bfloat162float(sftsh[(size_t)d0 * 64 + lane]);
            float v1 = __bfloat162float(sftsh[(size_t)d1 * 64 + lane]);
            float v2 = __bfloat162float(sftsh[(size_t)d2 * 64 + lane]);
            float v3 = __bfloat162float(sftsh[(size_t)d3 * 64 + lane]);
            float v4 = __bfloat162float(sftsh[(size_t)d4 * 64 + lane]);
            float v5 = __bfloat162float(sftsh[(size_t)d5 * 64 + lane]);
            float v6 = __bfloat162float(sftsh[(size_t)d6 * 64 + lane]);
            float v7 = __bfloat162float(sftsh[(size_t)d7 * 64 + lane]);
            acc = fmaf(c0, v0, acc); acc = fmaf(c1, v1, acc);
            acc = fmaf(c2, v2, acc); acc = fmaf(c3, v3, acc);
            acc = fmaf(c4, v4, acc); acc = fmaf(c5, v5, acc);
            acc = fmaf(c6, v6, acc); acc = fmaf(c7, v7, acc);
        }
    }
    const size_t idx = (size_t)n * 64 + lane;
    float x = out[idx] + acc;
    out[idx] = (x > 0.f) ? x : expm1f(x);
}

extern "C" void kernel_launch(void* const* d_in, const int* in_sizes, int n_in,
                              void* d_out, int out_size, void* d_ws, size_t ws_size,
                              hipStream_t stream) {
    const float* seq  = (const float*)d_in[0];
    const int*   ei   = (const int*)d_in[1];
    const float* Wseq = (const float*)d_in[2];
    const float* wf1  = (const float*)d_in[3];
    const float* bf1  = (const float*)d_in[4];
    const float* wf2  = (const float*)d_in[5];
    const float* bf2  = (const float*)d_in[6];
    const float* bias = (const float*)d_in[7];
    const float* Wres = (const float*)d_in[8];
    const float* bres = (const float*)d_in[9];
    float* out = (float*)d_out;

    // ws layout (u32 units unless noted)
    unsigned* pmax1     = (unsigned*)d_ws;
    unsigned* pmax2     = (unsigned*)d_ws + 1;
    float*    psum      = (float*)d_ws + 2;
    unsigned* counts    = (unsigned*)d_ws + 16;
    unsigned* offs      = counts + N_NODES;               // N_NODES+1
    unsigned* bucketSum = offs + N_NODES + 1;             // NB
    unsigned* bucketOff = bucketSum + NB;                 // NB+1
    unsigned* cursor    = bucketOff + NB + 1;             // N_NODES
    unsigned short* sDst = (unsigned short*)(cursor + N_NODES);    // N_EDGES u16
    __hip_bfloat16* sftsh = (__hip_bfloat16*)(sDst + N_EDGES);     // N*64 bf16
    float*    f1        = (float*)(sftsh + (size_t)N_NODES * 64);
    float*    f2        = f1 + N_NODES;
    // total ~11 MB

    k_zero<<<196, 256, 0, stream>>>(pmax1, pmax2, psum, counts);
    k_hist<<<2048, 256, 0, stream>>>(ei, counts);
    k_gemm<<<782, 256, 0, stream>>>(seq, Wseq, Wres, wf1, bf1, wf2, bf2, bias,
                                    bres, sftsh, f1, f2, pmax1, pmax2, out);
    k_scanA<<<196, 256, 0, stream>>>(counts, bucketSum);
    k_scanB<<<1, 1024, 0, stream>>>(bucketSum, bucketOff, offs);
    k_scanC<<<196, 256, 0, stream>>>(counts, bucketOff, offs, cursor);
    k_placesum<<<2048, 256, 0, stream>>>(ei, f1, f2, pmax1, pmax2, cursor, sDst, psum);
    k_acc<<<12500, 256, 0, stream>>>(offs, sDst, f1, f2, sftsh, pmax1, pmax2, psum, out);
}